// Round 9
// baseline (954.465 us; speedup 1.0000x reference)
//
#include <hip/hip_runtime.h>
#include <math.h>

#define B_DIM 4
#define T_DIM 2048
#define D_DIM 1024
#define ETA 0.1f
#define N_ITERS 10

typedef unsigned short u16;
typedef __attribute__((ext_vector_type(8))) short bf8_t;   // 8 bf16 (4 VGPRs)
typedef __attribute__((ext_vector_type(4))) float f4_t;    // 4 fp32 acc
typedef __attribute__((ext_vector_type(16))) float f16v;   // 16 fp32 acc (32x32)

__device__ __forceinline__ u16 f2bf(float f) {
  union { float f; unsigned u; } x;
  x.f = f;
  unsigned r = x.u + 0x7FFFu + ((x.u >> 16) & 1u);  // RNE
  return (u16)(r >> 16);
}
__device__ __forceinline__ float bf2f(u16 h) {
  union { unsigned u; float f; } x;
  x.u = ((unsigned)h) << 16;
  return x.f;
}

__device__ __forceinline__ float soft_thresh(float v, float lam) {
  return copysignf(fmaxf(fabsf(v) - lam, 0.0f), v);
}

// ---------------------------------------------------------------------------
// Async global -> LDS staging, 16B per lane (ladder step-3, m97 pattern).
// HW semantics: LDS dest = wave-uniform base + lane*16; global src per-lane.
// ---------------------------------------------------------------------------
__device__ __forceinline__ void gload16(const u16* g, u16* l) {
  __builtin_amdgcn_global_load_lds(
      (const __attribute__((address_space(1))) unsigned int*)g,
      (__attribute__((address_space(3))) unsigned int*)l, 16, 0, 0);
}

// ---------------------------------------------------------------------------
// bf16 MFMA NT GEMM core v2: C(128x128 at m0,n0) = A[M x K] * B^T (B [N][K]).
// 256 threads = 4 waves (2x2), each wave 64x64 = 4x4 mfma 16x16x32 tiles.
// global_load_lds width=16 into LINEAR [128][64] LDS (R7-proven: non-LCA
// half 670 -> 266us). Do not modify.
// ---------------------------------------------------------------------------
__device__ __forceinline__ void mfma_gemm_nt(const u16* __restrict__ A,
                                             const u16* __restrict__ Bm,
                                             int lda, int ldb,
                                             int m0, int n0, int kEnd,
                                             f4_t acc[4][4]) {
  __shared__ u16 As[128][64];
  __shared__ u16 Bs[128][64];
  const int tid = threadIdx.x;
  const int lane = tid & 63;
  const int wave = tid >> 6;
  const int m16 = lane & 15;
  const int q = lane >> 4;
  const int wrow = (wave >> 1) * 64;
  const int wcol = (wave & 1) * 64;
  const int sr = tid >> 3;   // staging row base (0..31)
  const int sc8 = tid & 7;   // k-octet (8 bf16 = 16B)

  u16* aB = &As[0][0] + wave * 512;   // wave-uniform LDS dest (1 KiB / wave)
  u16* bB = &Bs[0][0] + wave * 512;

  for (int k0 = 0; k0 < kEnd; k0 += 64) {
    __syncthreads();   // previous tile fully consumed; safe to overwrite
#pragma unroll
    for (int p = 0; p < 4; ++p) {
      gload16(A + (size_t)(m0 + sr + p * 32) * lda + k0 + sc8 * 8,
              aB + p * 2048);
      gload16(Bm + (size_t)(n0 + sr + p * 32) * ldb + k0 + sc8 * 8,
              bB + p * 2048);
    }
    __syncthreads();   // compiler drains vmcnt(0) before barrier -> data ready
#pragma unroll
    for (int s = 0; s < 2; ++s) {
      bf8_t af[4], bb[4];
#pragma unroll
      for (int i = 0; i < 4; ++i)
        af[i] = *(const bf8_t*)&As[wrow + i * 16 + m16][s * 32 + q * 8];
#pragma unroll
      for (int j = 0; j < 4; ++j)
        bb[j] = *(const bf8_t*)&Bs[wcol + j * 16 + m16][s * 32 + q * 8];
#pragma unroll
      for (int i = 0; i < 4; ++i)
#pragma unroll
        for (int j = 0; j < 4; ++j)
          acc[i][j] = __builtin_amdgcn_mfma_f32_16x16x32_bf16(
              af[i], bb[j], acc[i][j], 0, 0, 0);
    }
  }
}

// C/D layout 16x16 (verified m89): col = lane&15, row = (lane>>4)*4 + reg.
#define EPI_PREAMBLE                                   \
  const int tid = threadIdx.x;                         \
  const int lane = tid & 63;                           \
  const int wave = tid >> 6;                           \
  const int m16 = lane & 15;                           \
  const int q = lane >> 4;                             \
  const int wrow = (wave >> 1) * 64;                   \
  const int wcol = (wave & 1) * 64;

// ---------------------------------------------------------------------------
// Merged fp32 -> bf16 conversion for x, Wqkv, Wout in one dispatch.
// Also zeroes the 8-int LCA alignment-semaphore array (runs before LCA).
// ---------------------------------------------------------------------------
__global__ __launch_bounds__(256) void cvt_all_kernel(
    const float* __restrict__ x, u16* __restrict__ xb, int nx4,
    const float* __restrict__ w1, u16* __restrict__ w1b, int nw14,
    const float* __restrict__ w2, u16* __restrict__ w2b, int nw24,
    int* __restrict__ sem) {
  if (blockIdx.x == 0 && threadIdx.x < 8) sem[threadIdx.x] = 0;
  int i = blockIdx.x * 256 + threadIdx.x;
  const float* src;
  u16* dst;
  if (i < nx4) {
    src = x; dst = xb;
  } else if (i < nx4 + nw14) {
    i -= nx4; src = w1; dst = w1b;
  } else {
    i -= nx4 + nw14;
    if (i >= nw24) return;
    src = w2; dst = w2b;
  }
  const float4 v = ((const float4*)src)[i];
  ushort4 o;
  o.x = f2bf(v.x); o.y = f2bf(v.y); o.z = f2bf(v.z); o.w = f2bf(v.w);
  ((ushort4*)dst)[i] = o;
}

// ---------------------------------------------------------------------------
// G -> fragment-sequential swizzled layout, PRE-SCALED by -ETA:
// Gsw holds -eta * (0.5*(Graw+Graw^T)), zero diag. With the accumulator
// entering the K-loop as (1-eta)*v + eta*u, the MFMA chain then directly
// produces v' = (1-eta)v + eta*u - eta*(a@G) -- v lives in acc registers.
// flat = ((T*64 + c)*64 + w)*8 + j holds G[n][k], n = T*32 + (w&31),
// k = c*16 + (w>>5)*8 + j.
// ---------------------------------------------------------------------------
__global__ __launch_bounds__(256) void prep_Gsw_kernel(
    const float* __restrict__ Graw, u16* __restrict__ Gsw) {
  __shared__ float At[64][65];   // Graw[N0+i][K0+j]
  __shared__ float Bt[64][65];   // Graw[K0+i][N0+j]
  const int K0 = (blockIdx.x & 15) * 64;
  const int N0 = (blockIdx.x >> 4) * 64;
  const int tid = threadIdx.x;
  const int row = tid >> 2;          // 0..63
  const int c4b = tid & 3;           // float4 column group base
#pragma unroll
  for (int rep = 0; rep < 4; ++rep) {
    const int c4 = c4b + rep * 4;    // 0..15
    *(float4*)&At[row][c4 * 4] =
        *(const float4*)(Graw + (size_t)(N0 + row) * D_DIM + K0 + c4 * 4);
    *(float4*)&Bt[row][c4 * 4] =
        *(const float4*)(Graw + (size_t)(K0 + row) * D_DIM + N0 + c4 * 4);
  }
  __syncthreads();
  const float s = -ETA * 0.5f;
#pragma unroll
  for (int rep = 0; rep < 2; ++rep) {
    const int task = tid + rep * 256;   // 0..511
    const int tc = task >> 6;           // 0..7
    const int w = task & 63;
    const int t_l = tc >> 2;            // 0..1
    const int c_l = tc & 3;             // 0..3
    const int i = t_l * 32 + (w & 31);          // n-local
    const int kb = c_l * 16 + (w >> 5) * 8;     // k-local base
    union { u16 sdat[8]; float4 v; } o;
#pragma unroll
    for (int j = 0; j < 8; ++j) {
      const int kl = kb + j;
      const float g = (N0 + i == K0 + kl)
          ? 0.0f
          : s * (At[i][kl] + Bt[kl][i]);
      o.sdat[j] = f2bf(g);
    }
    const size_t T = (size_t)(N0 >> 5) + t_l;
    const size_t c = (size_t)(K0 >> 4) + c_l;
    *(float4*)(Gsw + ((T * 64 + c) * 64 + w) * 8) = o.v;
  }
}

// ---------------------------------------------------------------------------
// qkv = x @ Wqkv^T -> all outputs bf16: uqb / ukb (in d_out) / vbf.
// 1-D grid of 1536 blocks, supertile-swizzled (R7-proven).
// ---------------------------------------------------------------------------
__global__ __launch_bounds__(256) void qkv_mfma_kernel(
    const u16* __restrict__ xbf, const u16* __restrict__ Wbf,
    u16* __restrict__ uqb, u16* __restrict__ ukb, u16* __restrict__ vbf) {
  const int bid = blockIdx.x;
  const int g = bid / 192;
  const int r = bid % 192;
  const int m0 = (g * 8 + (r & 7)) * 128;
  const int n0 = (r >> 3) * 128;
  f4_t acc[4][4];
#pragma unroll
  for (int i = 0; i < 4; ++i)
#pragma unroll
    for (int j = 0; j < 4; ++j) acc[i][j] = (f4_t){0.f, 0.f, 0.f, 0.f};
  mfma_gemm_nt(xbf, Wbf, D_DIM, D_DIM, m0, n0, D_DIM, acc);
  EPI_PREAMBLE
  const int which = n0 >> 10;
  u16* dst = (which == 0) ? uqb : ((which == 1) ? ukb : vbf);
  const int nloc0 = n0 & 1023;
#pragma unroll
  for (int i = 0; i < 4; ++i)
#pragma unroll
    for (int j = 0; j < 4; ++j) {
      const int cc = nloc0 + wcol + j * 16 + m16;
#pragma unroll
      for (int r2 = 0; r2 < 4; ++r2) {
        const size_t rr = m0 + wrow + i * 16 + q * 4 + r2;
        dst[rr * D_DIM + cc] = f2bf(acc[i][j][r2]);
      }
    }
}

// ---------------------------------------------------------------------------
__global__ __launch_bounds__(256) void transpose_bf16_kernel(
    const u16* __restrict__ src, u16* __restrict__ dst) {
  __shared__ short Ls[64][72];
  const int b = blockIdx.z;
  const int d0 = blockIdx.x * 64;
  const int t0 = blockIdx.y * 64;
  const int tid = threadIdx.x;
#pragma unroll
  for (int rep = 0; rep < 2; ++rep) {
    const int u = rep * 256 + tid;
    const int r = u >> 3;
    const int c8 = u & 7;
    const float4 v = *(const float4*)(src + (size_t)b * T_DIM * D_DIM +
                                      (size_t)(t0 + r) * D_DIM + d0 + c8 * 8);
    *(float4*)&Ls[r][c8 * 8] = v;
  }
  __syncthreads();
#pragma unroll
  for (int rep = 0; rep < 2; ++rep) {
    const int u = rep * 256 + tid;
    const int d = u >> 3;
    const int t8 = u & 7;
    union { u16 s[8]; float4 v; } tmp;
#pragma unroll
    for (int l = 0; l < 8; ++l) tmp.s[l] = (u16)Ls[t8 * 8 + l][d];
    *(float4*)(dst + (size_t)b * D_DIM * T_DIM + (size_t)(d0 + d) * T_DIM +
               t0 + t8 * 8) = tmp.v;
  }
}

// ---------------------------------------------------------------------------
// Fused LCA chain v14 = EXACT v6 hot loop + best-effort block alignment.
// R8 post-mortem: 3-buffer prefetch null (524 vs 518) -> the c-loop is
// G-DELIVERY-BOUND at 30 B/cyc/CU (c-step 2133 cyc = 64KB/30B;
// MfmaUtil 516/2133=24% matches measured 26.7%; VALUBusy 406/2133=19%
// matches 18.6%). The 2 co-resident blocks per CU are the SAME chain and
// read byte-identical G sequences; aligned within ~1 c-step (32KB = L1),
// the second block hits L1 on the first's fills -> per-CU L2 pull halves.
// v14 adds a monotonic per-(b&7)-group arrival counter: thread 0 arrives,
// then spins until all 64 same-G blocks reach this iteration OR a 16k-cyc
// timeout (correctness never depends on co-residency -- G16-safe hint).
// Spin is OUTSIDE the c-loop/epilogue; c-loop + epilogue byte-exact v6.
// ---------------------------------------------------------------------------
__global__ __launch_bounds__(512) void lca_fused_kernel(
    const u16* __restrict__ uqb, const u16* __restrict__ ukb,
    const u16* __restrict__ Gqsw, const u16* __restrict__ Gksw,
    const float* __restrict__ llq, const float* __restrict__ llk,
    u16* __restrict__ aq_out, u16* __restrict__ ak_out,
    int* __restrict__ sem) {
  __shared__ u16 a_lds[32][1032];
  const int b = blockIdx.x;
  const int chain = (b >> 2) & 1;                 // b%8: 0-3 q, 4-7 k (XCD map)
  const int mb = ((b >> 3) << 2) | (b & 3);       // 0..255
  const int m0 = mb * 32;
  const u16* __restrict__ ub = chain ? ukb : uqb;
  const u16* __restrict__ Gsw = chain ? Gksw : Gqsw;
  u16* __restrict__ aout = chain ? ak_out : aq_out;
  const float lam = expf(chain ? llk[0] : llq[0]);

  const int tid = threadIdx.x;
  const int lane = tid & 63;
  const int wave = tid >> 6;      // 0..7
  const int n32 = lane & 31;
  const int l5 = lane >> 5;       // 0/1
  const int col0 = wave * 128;
  int* grp_sem = sem + (b & 7);   // 64 blocks share one counter (same G)

  f16v acc[4];                    // acc[nt] = v for this wave's 4 n-tiles

  // ---- init (iter 0): v1 = ETA*u ; a1 = soft(v1) -> LDS ;
  //      then pre-scale for iter 1: acc = (1-ETA)*v1 + ETA*u  (reuse uu)
#pragma unroll
  for (int nt = 0; nt < 4; ++nt) {
    const int col_g = col0 + nt * 32 + n32;
#pragma unroll
    for (int reg = 0; reg < 16; ++reg) {
      const int row = (reg & 3) + 8 * (reg >> 2) + 4 * l5;
      const float uu = bf2f(ub[(size_t)(m0 + row) * D_DIM + col_g]);
      const float v1 = ETA * uu;
      a_lds[row][col_g] = f2bf(soft_thresh(v1, lam));
      acc[nt][reg] = (1.0f - ETA) * v1 + ETA * uu;
    }
  }

  // per-tile fragment base: Gsw + t*64*512 + lane*8 (elems); step c = +512
  const u16* gb[4];
#pragma unroll
  for (int nt = 0; nt < 4; ++nt)
    gb[nt] = Gsw + ((size_t)(wave * 4 + nt) * 64) * 512 + lane * 8;

  for (int it = 1; it < N_ITERS; ++it) {
    // Best-effort alignment of the 64 same-G blocks (L1-sharing hint).
    if (tid == 0) {
      __hip_atomic_fetch_add(grp_sem, 1, __ATOMIC_RELAXED,
                             __HIP_MEMORY_SCOPE_AGENT);
      const int target = 64 * it;
      const unsigned long long t0 = clock64();
      while (__hip_atomic_load(grp_sem, __ATOMIC_RELAXED,
                               __HIP_MEMORY_SCOPE_AGENT) < target &&
             (clock64() - t0) < 16384ull) {
        __builtin_amdgcn_s_sleep(2);
      }
    }
    __syncthreads();  // a_lds complete (init or previous epilogue) + spin done

    bf8_t bb0[4], bb1[4];
#pragma unroll
    for (int nt = 0; nt < 4; ++nt) bb0[nt] = *(const bf8_t*)(gb[nt]);

#pragma unroll 1
    for (int c = 0; c < 64; c += 2) {
#pragma unroll
      for (int nt = 0; nt < 4; ++nt)
        bb1[nt] = *(const bf8_t*)(gb[nt] + (size_t)(c + 1) * 512);
      {
        const bf8_t af = *(const bf8_t*)&a_lds[n32][c * 16 + l5 * 8];
#pragma unroll
        for (int nt = 0; nt < 4; ++nt)
          acc[nt] = __builtin_amdgcn_mfma_f32_32x32x16_bf16(af, bb0[nt],
                                                            acc[nt], 0, 0, 0);
      }
      if (c + 2 < 64) {
#pragma unroll
        for (int nt = 0; nt < 4; ++nt)
          bb0[nt] = *(const bf8_t*)(gb[nt] + (size_t)(c + 2) * 512);
      }
      {
        const bf8_t af = *(const bf8_t*)&a_lds[n32][(c + 1) * 16 + l5 * 8];
#pragma unroll
        for (int nt = 0; nt < 4; ++nt)
          acc[nt] = __builtin_amdgcn_mfma_f32_32x32x16_bf16(af, bb1[nt],
                                                            acc[nt], 0, 0, 0);
      }
    }
    __syncthreads();  // all waves done READING a_lds; safe to overwrite

    // acc now holds v_{t+1}. Epilogue: a -> LDS (+global on last);
    // then pre-scale acc for the next iteration.
    const bool last = (it == N_ITERS - 1);
#pragma unroll
    for (int nt = 0; nt < 4; ++nt) {
      const int col_g = col0 + nt * 32 + n32;
#pragma unroll
      for (int reg = 0; reg < 16; ++reg) {
        const int row = (reg & 3) + 8 * (reg >> 2) + 4 * l5;
        const u16 av = f2bf(soft_thresh(acc[nt][reg], lam));
        a_lds[row][col_g] = av;
        if (last) {
          aout[(size_t)(m0 + row) * D_DIM + col_g] = av;
        } else {
          const float uu = bf2f(ub[(size_t)(m0 + row) * D_DIM + col_g]);
          acc[nt][reg] = (1.0f - ETA) * acc[nt][reg] + ETA * uu;
        }
      }
    }
  }
}

// ---------------------------------------------------------------------------
__global__ __launch_bounds__(256) void scores_mfma_kernel(
    const u16* __restrict__ aq, const u16* __restrict__ ak,
    float* __restrict__ sc) {
  const int b = blockIdx.z;
  const int m0 = blockIdx.y * 128;
  const int n0 = blockIdx.x * 128;
  if (n0 > m0 + 127) return;  // uniform early exit, before any barrier
  f4_t acc[4][4];
#pragma unroll
  for (int i = 0; i < 4; ++i)
#pragma unroll
    for (int j = 0; j < 4; ++j) acc[i][j] = (f4_t){0.f, 0.f, 0.f, 0.f};
  mfma_gemm_nt(aq + (size_t)b * T_DIM * D_DIM,
               ak + (size_t)b * T_DIM * D_DIM, D_DIM, D_DIM, m0, n0, D_DIM,
               acc);
  EPI_PREAMBLE
  float* out = sc + (size_t)b * T_DIM * T_DIM;
  const float scale = 0.03125f;  // 1/sqrt(1024)
#pragma unroll
  for (int i = 0; i < 4; ++i)
#pragma unroll
    for (int j = 0; j < 4; ++j) {
      const int cc = n0 + wcol + j * 16 + m16;
#pragma unroll
      for (int r = 0; r < 4; ++r) {
        const size_t rr = m0 + wrow + i * 16 + q * 4 + r;
        out[rr * T_DIM + cc] = acc[i][j][r] * scale;
      }
    }
}

// ---------------------------------------------------------------------------
// Causal softmax, one WAVE per row: row cached in 32 statically-indexed
// registers -> sc read ONCE (was 3x). exp reused from the cached value.
// ---------------------------------------------------------------------------
__global__ __launch_bounds__(256) void softmax_attn_kernel(
    const float* __restrict__ sc, u16* __restrict__ attn) {
  const int r = blockIdx.x * 4 + (threadIdx.x >> 6);  // global row 0..8191
  const int lane = threadIdx.x & 63;
  const int b = r >> 11;
  const int i = r & (T_DIM - 1);
  const float* row = sc + ((size_t)b * T_DIM + i) * T_DIM;
  u16* arow = attn + ((size_t)b * T_DIM + i) * T_DIM;
  const int len = i + 1;

  float v[32];
  float mx = -INFINITY;
#pragma unroll
  for (int jj = 0; jj < 32; ++jj) {
    const int j = lane + jj * 64;
    v[jj] = (j < len) ? row[j] : -INFINITY;
    mx = fmaxf(mx, v[jj]);
  }
#pragma unroll
  for (int off = 32; off > 0; off >>= 1)
    mx = fmaxf(mx, __shfl_xor(mx, off));

  float sum = 0.0f;
#pragma unroll
  for (int jj = 0; jj < 32; ++jj) {
    const float e = __expf(v[jj] - mx);  // -inf -> 0
    v[jj] = e;
    sum += e;
  }
#pragma unroll
  for (int off = 32; off > 0; off >>= 1) sum += __shfl_xor(sum, off);
  const float inv = 1.0f / sum;

#pragma unroll
  for (int jj = 0; jj < 32; ++jj) {
    const int j = lane + jj * 64;
    arow[j] = (j < len) ? f2bf(v[jj] * inv) : (u16)0;
  }
}

// ---------------------------------------------------------------------------
__global__ __launch_bounds__(256) void attnv_mfma_kernel(
    const u16* __restrict__ attn, const u16* __restrict__ vT,
    u16* __restrict__ o1) {
  const int b = blockIdx.z;
  const int m0 = blockIdx.y * 128;
  const int n0 = blockIdx.x * 128;
  f4_t acc[4][4];
#pragma unroll
  for (int i = 0; i < 4; ++i)
#pragma unroll
    for (int j = 0; j < 4; ++j) acc[i][j] = (f4_t){0.f, 0.f, 0.f, 0.f};
  mfma_gemm_nt(attn + (size_t)b * T_DIM * T_DIM,
               vT + (size_t)b * D_DIM * T_DIM, T_DIM, T_DIM, m0, n0,
               m0 + 128, acc);
  EPI_PREAMBLE
  u16* out = o1 + (size_t)b * T_DIM * D_DIM;
#pragma unroll
  for (int i = 0; i < 4; ++i)
#pragma unroll
    for (int j = 0; j < 4; ++j) {
      const int cc = n0 + wcol + j * 16 + m16;
#pragma unroll
      for (int r = 0; r < 4; ++r) {
        const size_t rr = m0 + wrow + i * 16 + q * 4 + r;
        out[rr * D_DIM + cc] = f2bf(acc[i][j][r]);
      }
    }
}

// ---------------------------------------------------------------------------
__global__ __launch_bounds__(256) void out_mfma_kernel(
    const u16* __restrict__ o1, const u16* __restrict__ Wbf,
    float* __restrict__ out) {
  f4_t acc[4][4];
#pragma unroll
  for (int i = 0; i < 4; ++i)
#pragma unroll
    for (int j = 0; j < 4; ++j) acc[i][j] = (f4_t){0.f, 0.f, 0.f, 0.f};
  const int m0 = blockIdx.y * 128;
  const int n0 = blockIdx.x * 128;
  mfma_gemm_nt(o1, Wbf, D_DIM, D_DIM, m0, n0, D_DIM, acc);
  EPI_PREAMBLE
#pragma unroll
  for (int i = 0; i < 4; ++i)
#pragma unroll
    for (int j = 0; j < 4; ++j) {
      const int cc = n0 + wcol + j * 16 + m16;
#pragma unroll
      for (int r = 0; r < 4; ++r) {
        const size_t rr = m0 + wrow + i * 16 + q * 4 + r;
        out[rr * D_DIM + cc] = acc[i][j][r];
      }
    }
}

// ---------------------------------------------------------------------------
// Workspace (SZ = B*T*D = 8,388,608), total ~156 MiB (proven):
//   R0: 2*SZ fp32 (64 MiB) = scores; hosts xbf (bf16 x) early (dead by then)
//   uqb, vbf, vT, bq1(aq), bkf(ak): 5 x SZ u16 (80 MiB)
//   wqkvb 3M, woutb 1M, gqsw 1M, gksw 1M u16 (12 MiB) + 8-int sem
// ukb (bf16 u_k) lives in d_out, fully overwritten by the final GEMM.
// attn (2*SZ u16) over [bq1|bkf] (dead after scores); o1 over uqb (dead).
// ---------------------------------------------------------------------------
extern "C" void kernel_launch(void* const* d_in, const int* in_sizes, int n_in,
                              void* d_out, int out_size, void* d_ws,
                              size_t ws_size, hipStream_t stream) {
  (void)in_sizes; (void)n_in; (void)out_size; (void)ws_size;
  const float* x = (const float*)d_in[0];
  const float* Wqkv = (const float*)d_in[1];
  const float* Wout = (const float*)d_in[2];
  const float* Gq_raw = (const float*)d_in[3];
  const float* llq = (const float*)d_in[4];
  const float* Gk_raw = (const float*)d_in[5];
  const float* llk = (const float*)d_in[6];
  float* out = (float*)d_out;

  const size_t SZ = (size_t)B_DIM * T_DIM * D_DIM;  // 8,388,608
  u16* base = (u16*)d_ws;
  float* sc = (float*)base;          // 2*SZ fp32 (= 4*SZ u16)
  u16* xbf = base;                   // bf16 x over R0 start (dead before sc)
  u16* uqb = base + 4 * SZ;
  u16* vbf = base + 5 * SZ;
  u16* vT  = base + 6 * SZ;
  u16* bq1 = base + 7 * SZ;          // final aq
  u16* bkf = base + 8 * SZ;          // final ak
  u16* wqkvb = base + 9 * SZ;                    // 3M
  u16* woutb = wqkvb + 3 * 1024 * 1024;          // 1M
  u16* gqsw = woutb + 1024 * 1024;               // 1M
  u16* gksw = gqsw + 1024 * 1024;                // 1M
  int* sem = (int*)(gksw + 1024 * 1024);         // 8 ints
  u16* ukb = (u16*)d_out;            // bf16 u_k in d_out until final GEMM
  u16* attn = bq1;                   // 2*SZ over bq1+bkf (dead after scores)
  u16* o1 = uqb;                     // dead after LCA

  const dim3 blk(256);

  // merged fp32->bf16 conversions (+ sem zeroing)
  cvt_all_kernel<<<dim3(12288), blk, 0, stream>>>(
      x, xbf, (int)(SZ / 4), Wqkv, wqkvb, 3 * 1024 * 1024 / 4, Wout, woutb,
      1024 * 1024 / 4, sem);
  prep_Gsw_kernel<<<dim3(256), blk, 0, stream>>>(Gq_raw, gqsw);
  prep_Gsw_kernel<<<dim3(256), blk, 0, stream>>>(Gk_raw, gksw);

  // qkv: 1536 blocks, supertile-swizzled; bf16 outputs
  qkv_mfma_kernel<<<dim3(1536), blk, 0, stream>>>(xbf, wqkvb, uqb, ukb, vbf);
  transpose_bf16_kernel<<<dim3(16, 32, 4), blk, 0, stream>>>(vbf, vT);

  // fused LCA v14 (= v6 + best-effort group alignment): one dispatch
  lca_fused_kernel<<<dim3(512), dim3(512), 0, stream>>>(uqb, ukb, gqsw, gksw,
                                                        llq, llk, bq1, bkf,
                                                        sem);

  scores_mfma_kernel<<<dim3(16, 16, 4), blk, 0, stream>>>(bq1, bkf, sc);
  softmax_attn_kernel<<<dim3(B_DIM * T_DIM / 4), blk, 0, stream>>>(sc, attn);
  attnv_mfma_kernel<<<dim3(8, 16, 4), blk, 0, stream>>>(attn, vT, o1);
  out_mfma_kernel<<<dim3(8, 64), blk, 0, stream>>>(o1, woutb, out);
}

// Round 10
// 780.156 us; speedup vs baseline: 1.2234x; 1.2234x over previous
//
#include <hip/hip_runtime.h>
#include <math.h>

#define B_DIM 4
#define T_DIM 2048
#define D_DIM 1024
#define ETA 0.1f
#define N_ITERS 10

typedef unsigned short u16;
typedef __attribute__((ext_vector_type(8))) short bf8_t;   // 8 bf16 (4 VGPRs)
typedef __attribute__((ext_vector_type(4))) float f4_t;    // 4 fp32 acc
typedef __attribute__((ext_vector_type(16))) float f16v;   // 16 fp32 acc (32x32)

__device__ __forceinline__ u16 f2bf(float f) {
  union { float f; unsigned u; } x;
  x.f = f;
  unsigned r = x.u + 0x7FFFu + ((x.u >> 16) & 1u);  // RNE
  return (u16)(r >> 16);
}
__device__ __forceinline__ float bf2f(u16 h) {
  union { unsigned u; float f; } x;
  x.u = ((unsigned)h) << 16;
  return x.f;
}

__device__ __forceinline__ float soft_thresh(float v, float lam) {
  return copysignf(fmaxf(fabsf(v) - lam, 0.0f), v);
}

// ---------------------------------------------------------------------------
// Async global -> LDS staging, 16B per lane (ladder step-3, m97 pattern).
// HW semantics: LDS dest = wave-uniform base + lane*16; global src per-lane.
// ---------------------------------------------------------------------------
__device__ __forceinline__ void gload16(const u16* g, u16* l) {
  __builtin_amdgcn_global_load_lds(
      (const __attribute__((address_space(1))) unsigned int*)g,
      (__attribute__((address_space(3))) unsigned int*)l, 16, 0, 0);
}

// ---------------------------------------------------------------------------
// bf16 MFMA NT GEMM core v2: C(128x128 at m0,n0) = A[M x K] * B^T (B [N][K]).
// 256 threads = 4 waves (2x2), each wave 64x64 = 4x4 mfma 16x16x32 tiles.
// global_load_lds width=16 into LINEAR [128][64] LDS (R7-proven: non-LCA
// half 670 -> 266us). Do not modify.
// ---------------------------------------------------------------------------
__device__ __forceinline__ void mfma_gemm_nt(const u16* __restrict__ A,
                                             const u16* __restrict__ Bm,
                                             int lda, int ldb,
                                             int m0, int n0, int kEnd,
                                             f4_t acc[4][4]) {
  __shared__ u16 As[128][64];
  __shared__ u16 Bs[128][64];
  const int tid = threadIdx.x;
  const int lane = tid & 63;
  const int wave = tid >> 6;
  const int m16 = lane & 15;
  const int q = lane >> 4;
  const int wrow = (wave >> 1) * 64;
  const int wcol = (wave & 1) * 64;
  const int sr = tid >> 3;   // staging row base (0..31)
  const int sc8 = tid & 7;   // k-octet (8 bf16 = 16B)

  u16* aB = &As[0][0] + wave * 512;   // wave-uniform LDS dest (1 KiB / wave)
  u16* bB = &Bs[0][0] + wave * 512;

  for (int k0 = 0; k0 < kEnd; k0 += 64) {
    __syncthreads();   // previous tile fully consumed; safe to overwrite
#pragma unroll
    for (int p = 0; p < 4; ++p) {
      gload16(A + (size_t)(m0 + sr + p * 32) * lda + k0 + sc8 * 8,
              aB + p * 2048);
      gload16(Bm + (size_t)(n0 + sr + p * 32) * ldb + k0 + sc8 * 8,
              bB + p * 2048);
    }
    __syncthreads();   // compiler drains vmcnt(0) before barrier -> data ready
#pragma unroll
    for (int s = 0; s < 2; ++s) {
      bf8_t af[4], bb[4];
#pragma unroll
      for (int i = 0; i < 4; ++i)
        af[i] = *(const bf8_t*)&As[wrow + i * 16 + m16][s * 32 + q * 8];
#pragma unroll
      for (int j = 0; j < 4; ++j)
        bb[j] = *(const bf8_t*)&Bs[wcol + j * 16 + m16][s * 32 + q * 8];
#pragma unroll
      for (int i = 0; i < 4; ++i)
#pragma unroll
        for (int j = 0; j < 4; ++j)
          acc[i][j] = __builtin_amdgcn_mfma_f32_16x16x32_bf16(
              af[i], bb[j], acc[i][j], 0, 0, 0);
    }
  }
}

// C/D layout 16x16 (verified m89): col = lane&15, row = (lane>>4)*4 + reg.
#define EPI_PREAMBLE                                   \
  const int tid = threadIdx.x;                         \
  const int lane = tid & 63;                           \
  const int wave = tid >> 6;                           \
  const int m16 = lane & 15;                           \
  const int q = lane >> 4;                             \
  const int wrow = (wave >> 1) * 64;                   \
  const int wcol = (wave & 1) * 64;

// ---------------------------------------------------------------------------
// Merged fp32 -> bf16 conversion for x, Wqkv, Wout in one dispatch.
// ---------------------------------------------------------------------------
__global__ __launch_bounds__(256) void cvt_all_kernel(
    const float* __restrict__ x, u16* __restrict__ xb, int nx4,
    const float* __restrict__ w1, u16* __restrict__ w1b, int nw14,
    const float* __restrict__ w2, u16* __restrict__ w2b, int nw24) {
  int i = blockIdx.x * 256 + threadIdx.x;
  const float* src;
  u16* dst;
  if (i < nx4) {
    src = x; dst = xb;
  } else if (i < nx4 + nw14) {
    i -= nx4; src = w1; dst = w1b;
  } else {
    i -= nx4 + nw14;
    if (i >= nw24) return;
    src = w2; dst = w2b;
  }
  const float4 v = ((const float4*)src)[i];
  ushort4 o;
  o.x = f2bf(v.x); o.y = f2bf(v.y); o.z = f2bf(v.z); o.w = f2bf(v.w);
  ((ushort4*)dst)[i] = o;
}

// ---------------------------------------------------------------------------
// G -> fragment-sequential swizzled layout, PRE-SCALED by -ETA:
// Gsw holds -eta * (0.5*(Graw+Graw^T)), zero diag. With the accumulator
// entering the K-loop as (1-eta)*v + eta*u, the MFMA chain then directly
// produces v' = (1-eta)v + eta*u - eta*(a@G) -- v lives in acc registers.
// flat = ((T*64 + c)*64 + w)*8 + j holds G[n][k], n = T*32 + (w&31),
// k = c*16 + (w>>5)*8 + j.
// ---------------------------------------------------------------------------
__global__ __launch_bounds__(256) void prep_Gsw_kernel(
    const float* __restrict__ Graw, u16* __restrict__ Gsw) {
  __shared__ float At[64][65];   // Graw[N0+i][K0+j]
  __shared__ float Bt[64][65];   // Graw[K0+i][N0+j]
  const int K0 = (blockIdx.x & 15) * 64;
  const int N0 = (blockIdx.x >> 4) * 64;
  const int tid = threadIdx.x;
  const int row = tid >> 2;          // 0..63
  const int c4b = tid & 3;           // float4 column group base
#pragma unroll
  for (int rep = 0; rep < 4; ++rep) {
    const int c4 = c4b + rep * 4;    // 0..15
    *(float4*)&At[row][c4 * 4] =
        *(const float4*)(Graw + (size_t)(N0 + row) * D_DIM + K0 + c4 * 4);
    *(float4*)&Bt[row][c4 * 4] =
        *(const float4*)(Graw + (size_t)(K0 + row) * D_DIM + N0 + c4 * 4);
  }
  __syncthreads();
  const float s = -ETA * 0.5f;
#pragma unroll
  for (int rep = 0; rep < 2; ++rep) {
    const int task = tid + rep * 256;   // 0..511
    const int tc = task >> 6;           // 0..7
    const int w = task & 63;
    const int t_l = tc >> 2;            // 0..1
    const int c_l = tc & 3;             // 0..3
    const int i = t_l * 32 + (w & 31);          // n-local
    const int kb = c_l * 16 + (w >> 5) * 8;     // k-local base
    union { u16 sdat[8]; float4 v; } o;
#pragma unroll
    for (int j = 0; j < 8; ++j) {
      const int kl = kb + j;
      const float g = (N0 + i == K0 + kl)
          ? 0.0f
          : s * (At[i][kl] + Bt[kl][i]);
      o.sdat[j] = f2bf(g);
    }
    const size_t T = (size_t)(N0 >> 5) + t_l;
    const size_t c = (size_t)(K0 >> 4) + c_l;
    *(float4*)(Gsw + ((T * 64 + c) * 64 + w) * 8) = o.v;
  }
}

// ---------------------------------------------------------------------------
// qkv = x @ Wqkv^T -> all outputs bf16: uqb / ukb (in d_out) / vbf.
// 1-D grid of 1536 blocks, supertile-swizzled (R7-proven).
// ---------------------------------------------------------------------------
__global__ __launch_bounds__(256) void qkv_mfma_kernel(
    const u16* __restrict__ xbf, const u16* __restrict__ Wbf,
    u16* __restrict__ uqb, u16* __restrict__ ukb, u16* __restrict__ vbf) {
  const int bid = blockIdx.x;
  const int g = bid / 192;
  const int r = bid % 192;
  const int m0 = (g * 8 + (r & 7)) * 128;
  const int n0 = (r >> 3) * 128;
  f4_t acc[4][4];
#pragma unroll
  for (int i = 0; i < 4; ++i)
#pragma unroll
    for (int j = 0; j < 4; ++j) acc[i][j] = (f4_t){0.f, 0.f, 0.f, 0.f};
  mfma_gemm_nt(xbf, Wbf, D_DIM, D_DIM, m0, n0, D_DIM, acc);
  EPI_PREAMBLE
  const int which = n0 >> 10;
  u16* dst = (which == 0) ? uqb : ((which == 1) ? ukb : vbf);
  const int nloc0 = n0 & 1023;
#pragma unroll
  for (int i = 0; i < 4; ++i)
#pragma unroll
    for (int j = 0; j < 4; ++j) {
      const int cc = nloc0 + wcol + j * 16 + m16;
#pragma unroll
      for (int r2 = 0; r2 < 4; ++r2) {
        const size_t rr = m0 + wrow + i * 16 + q * 4 + r2;
        dst[rr * D_DIM + cc] = f2bf(acc[i][j][r2]);
      }
    }
}

// ---------------------------------------------------------------------------
__global__ __launch_bounds__(256) void transpose_bf16_kernel(
    const u16* __restrict__ src, u16* __restrict__ dst) {
  __shared__ short Ls[64][72];
  const int b = blockIdx.z;
  const int d0 = blockIdx.x * 64;
  const int t0 = blockIdx.y * 64;
  const int tid = threadIdx.x;
#pragma unroll
  for (int rep = 0; rep < 2; ++rep) {
    const int u = rep * 256 + tid;
    const int r = u >> 3;
    const int c8 = u & 7;
    const float4 v = *(const float4*)(src + (size_t)b * T_DIM * D_DIM +
                                      (size_t)(t0 + r) * D_DIM + d0 + c8 * 8);
    *(float4*)&Ls[r][c8 * 8] = v;
  }
  __syncthreads();
#pragma unroll
  for (int rep = 0; rep < 2; ++rep) {
    const int u = rep * 256 + tid;
    const int d = u >> 3;
    const int t8 = u & 7;
    union { u16 s[8]; float4 v; } tmp;
#pragma unroll
    for (int l = 0; l < 8; ++l) tmp.s[l] = (u16)Ls[t8 * 8 + l][d];
    *(float4*)(dst + (size_t)b * D_DIM * T_DIM + (size_t)(d0 + d) * T_DIM +
               t0 + t8 * 8) = tmp.v;
  }
}

// ---------------------------------------------------------------------------
// Fused LCA chain v15 = EXACT v6 hot loop + per-block k-PHASE STAGGER.
// R9 post-mortem: aligning the 64 same-G blocks made c-steps SLOWER
// (MfmaUtil 26.7->19%) -> the limiter is L2 BANK CONCENTRATION, not missed
// L1 sharing. Per c-step a block reads 32 x 1KB chunks at ONE k-slice c;
// 64 co-XCD blocks in near-lockstep hammer the same 32KB of L2 while 98%
// of the 2MB G (and most L2 banks) idles -- measured 30 B/cyc/CU vs 56
// capability. v15: block rotates its fragment order by phase=(b>>3)&63
// (its XCD-local index), consuming idx(c)=(c+phase)&63. The 64 blocks then
// touch 64 DIFFERENT k-slices at any instant -> uniform bank spread.
// Same sum in rotated order (fp32 rounding delta ~1e-6, negligible).
// Rotation is address-indexing INSIDE the c-loop only (v13 showed in-loop
// reg growth does not trip the regalloc curse). Init/epilogue byte-exact v6.
// ---------------------------------------------------------------------------
__global__ __launch_bounds__(512) void lca_fused_kernel(
    const u16* __restrict__ uqb, const u16* __restrict__ ukb,
    const u16* __restrict__ Gqsw, const u16* __restrict__ Gksw,
    const float* __restrict__ llq, const float* __restrict__ llk,
    u16* __restrict__ aq_out, u16* __restrict__ ak_out) {
  __shared__ u16 a_lds[32][1032];
  const int b = blockIdx.x;
  const int chain = (b >> 2) & 1;                 // b%8: 0-3 q, 4-7 k (XCD map)
  const int mb = ((b >> 3) << 2) | (b & 3);       // 0..255
  const int m0 = mb * 32;
  const u16* __restrict__ ub = chain ? ukb : uqb;
  const u16* __restrict__ Gsw = chain ? Gksw : Gqsw;
  u16* __restrict__ aout = chain ? ak_out : aq_out;
  const float lam = expf(chain ? llk[0] : llq[0]);

  const int tid = threadIdx.x;
  const int lane = tid & 63;
  const int wave = tid >> 6;      // 0..7
  const int n32 = lane & 31;
  const int l5 = lane >> 5;       // 0/1
  const int col0 = wave * 128;
  const int phase = (b >> 3) & 63;   // XCD-local index: stagger k-slices

  f16v acc[4];                    // acc[nt] = v for this wave's 4 n-tiles

  // ---- init (iter 0): v1 = ETA*u ; a1 = soft(v1) -> LDS ;
  //      then pre-scale for iter 1: acc = (1-ETA)*v1 + ETA*u  (reuse uu)
#pragma unroll
  for (int nt = 0; nt < 4; ++nt) {
    const int col_g = col0 + nt * 32 + n32;
#pragma unroll
    for (int reg = 0; reg < 16; ++reg) {
      const int row = (reg & 3) + 8 * (reg >> 2) + 4 * l5;
      const float uu = bf2f(ub[(size_t)(m0 + row) * D_DIM + col_g]);
      const float v1 = ETA * uu;
      a_lds[row][col_g] = f2bf(soft_thresh(v1, lam));
      acc[nt][reg] = (1.0f - ETA) * v1 + ETA * uu;
    }
  }

  // per-tile fragment base: Gsw + t*64*512 + lane*8 (elems); step c = +512
  const u16* gb[4];
#pragma unroll
  for (int nt = 0; nt < 4; ++nt)
    gb[nt] = Gsw + ((size_t)(wave * 4 + nt) * 64) * 512 + lane * 8;

  for (int it = 1; it < N_ITERS; ++it) {
    __syncthreads();  // a_lds complete (init or previous epilogue)

    bf8_t bb0[4], bb1[4];
#pragma unroll
    for (int nt = 0; nt < 4; ++nt)
      bb0[nt] = *(const bf8_t*)(gb[nt] + (size_t)phase * 512);

#pragma unroll 1
    for (int c = 0; c < 64; c += 2) {
      const int i0 = (c + phase) & 63;
      const int i1 = (c + 1 + phase) & 63;
#pragma unroll
      for (int nt = 0; nt < 4; ++nt)
        bb1[nt] = *(const bf8_t*)(gb[nt] + (size_t)i1 * 512);
      {
        const bf8_t af = *(const bf8_t*)&a_lds[n32][i0 * 16 + l5 * 8];
#pragma unroll
        for (int nt = 0; nt < 4; ++nt)
          acc[nt] = __builtin_amdgcn_mfma_f32_32x32x16_bf16(af, bb0[nt],
                                                            acc[nt], 0, 0, 0);
      }
      if (c + 2 < 64) {
        const int i2 = (c + 2 + phase) & 63;
#pragma unroll
        for (int nt = 0; nt < 4; ++nt)
          bb0[nt] = *(const bf8_t*)(gb[nt] + (size_t)i2 * 512);
      }
      {
        const bf8_t af = *(const bf8_t*)&a_lds[n32][i1 * 16 + l5 * 8];
#pragma unroll
        for (int nt = 0; nt < 4; ++nt)
          acc[nt] = __builtin_amdgcn_mfma_f32_32x32x16_bf16(af, bb1[nt],
                                                            acc[nt], 0, 0, 0);
      }
    }
    __syncthreads();  // all waves done READING a_lds; safe to overwrite

    // acc now holds v_{t+1}. Epilogue: a -> LDS (+global on last);
    // then pre-scale acc for the next iteration.
    const bool last = (it == N_ITERS - 1);
#pragma unroll
    for (int nt = 0; nt < 4; ++nt) {
      const int col_g = col0 + nt * 32 + n32;
#pragma unroll
      for (int reg = 0; reg < 16; ++reg) {
        const int row = (reg & 3) + 8 * (reg >> 2) + 4 * l5;
        const u16 av = f2bf(soft_thresh(acc[nt][reg], lam));
        a_lds[row][col_g] = av;
        if (last) {
          aout[(size_t)(m0 + row) * D_DIM + col_g] = av;
        } else {
          const float uu = bf2f(ub[(size_t)(m0 + row) * D_DIM + col_g]);
          acc[nt][reg] = (1.0f - ETA) * acc[nt][reg] + ETA * uu;
        }
      }
    }
  }
}

// ---------------------------------------------------------------------------
__global__ __launch_bounds__(256) void scores_mfma_kernel(
    const u16* __restrict__ aq, const u16* __restrict__ ak,
    float* __restrict__ sc) {
  const int b = blockIdx.z;
  const int m0 = blockIdx.y * 128;
  const int n0 = blockIdx.x * 128;
  if (n0 > m0 + 127) return;  // uniform early exit, before any barrier
  f4_t acc[4][4];
#pragma unroll
  for (int i = 0; i < 4; ++i)
#pragma unroll
    for (int j = 0; j < 4; ++j) acc[i][j] = (f4_t){0.f, 0.f, 0.f, 0.f};
  mfma_gemm_nt(aq + (size_t)b * T_DIM * D_DIM,
               ak + (size_t)b * T_DIM * D_DIM, D_DIM, D_DIM, m0, n0, D_DIM,
               acc);
  EPI_PREAMBLE
  float* out = sc + (size_t)b * T_DIM * T_DIM;
  const float scale = 0.03125f;  // 1/sqrt(1024)
#pragma unroll
  for (int i = 0; i < 4; ++i)
#pragma unroll
    for (int j = 0; j < 4; ++j) {
      const int cc = n0 + wcol + j * 16 + m16;
#pragma unroll
      for (int r = 0; r < 4; ++r) {
        const size_t rr = m0 + wrow + i * 16 + q * 4 + r;
        out[rr * T_DIM + cc] = acc[i][j][r] * scale;
      }
    }
}

// ---------------------------------------------------------------------------
// Causal softmax, one WAVE per row: row cached in 32 statically-indexed
// registers -> sc read ONCE (was 3x). exp reused from the cached value.
// ---------------------------------------------------------------------------
__global__ __launch_bounds__(256) void softmax_attn_kernel(
    const float* __restrict__ sc, u16* __restrict__ attn) {
  const int r = blockIdx.x * 4 + (threadIdx.x >> 6);  // global row 0..8191
  const int lane = threadIdx.x & 63;
  const int b = r >> 11;
  const int i = r & (T_DIM - 1);
  const float* row = sc + ((size_t)b * T_DIM + i) * T_DIM;
  u16* arow = attn + ((size_t)b * T_DIM + i) * T_DIM;
  const int len = i + 1;

  float v[32];
  float mx = -INFINITY;
#pragma unroll
  for (int jj = 0; jj < 32; ++jj) {
    const int j = lane + jj * 64;
    v[jj] = (j < len) ? row[j] : -INFINITY;
    mx = fmaxf(mx, v[jj]);
  }
#pragma unroll
  for (int off = 32; off > 0; off >>= 1)
    mx = fmaxf(mx, __shfl_xor(mx, off));

  float sum = 0.0f;
#pragma unroll
  for (int jj = 0; jj < 32; ++jj) {
    const float e = __expf(v[jj] - mx);  // -inf -> 0
    v[jj] = e;
    sum += e;
  }
#pragma unroll
  for (int off = 32; off > 0; off >>= 1) sum += __shfl_xor(sum, off);
  const float inv = 1.0f / sum;

#pragma unroll
  for (int jj = 0; jj < 32; ++jj) {
    const int j = lane + jj * 64;
    arow[j] = (j < len) ? f2bf(v[jj] * inv) : (u16)0;
  }
}

// ---------------------------------------------------------------------------
__global__ __launch_bounds__(256) void attnv_mfma_kernel(
    const u16* __restrict__ attn, const u16* __restrict__ vT,
    u16* __restrict__ o1) {
  const int b = blockIdx.z;
  const int m0 = blockIdx.y * 128;
  const int n0 = blockIdx.x * 128;
  f4_t acc[4][4];
#pragma unroll
  for (int i = 0; i < 4; ++i)
#pragma unroll
    for (int j = 0; j < 4; ++j) acc[i][j] = (f4_t){0.f, 0.f, 0.f, 0.f};
  mfma_gemm_nt(attn + (size_t)b * T_DIM * T_DIM,
               vT + (size_t)b * D_DIM * T_DIM, T_DIM, T_DIM, m0, n0,
               m0 + 128, acc);
  EPI_PREAMBLE
  u16* out = o1 + (size_t)b * T_DIM * D_DIM;
#pragma unroll
  for (int i = 0; i < 4; ++i)
#pragma unroll
    for (int j = 0; j < 4; ++j) {
      const int cc = n0 + wcol + j * 16 + m16;
#pragma unroll
      for (int r = 0; r < 4; ++r) {
        const size_t rr = m0 + wrow + i * 16 + q * 4 + r;
        out[rr * D_DIM + cc] = f2bf(acc[i][j][r]);
      }
    }
}

// ---------------------------------------------------------------------------
__global__ __launch_bounds__(256) void out_mfma_kernel(
    const u16* __restrict__ o1, const u16* __restrict__ Wbf,
    float* __restrict__ out) {
  f4_t acc[4][4];
#pragma unroll
  for (int i = 0; i < 4; ++i)
#pragma unroll
    for (int j = 0; j < 4; ++j) acc[i][j] = (f4_t){0.f, 0.f, 0.f, 0.f};
  const int m0 = blockIdx.y * 128;
  const int n0 = blockIdx.x * 128;
  mfma_gemm_nt(o1, Wbf, D_DIM, D_DIM, m0, n0, D_DIM, acc);
  EPI_PREAMBLE
#pragma unroll
  for (int i = 0; i < 4; ++i)
#pragma unroll
    for (int j = 0; j < 4; ++j) {
      const int cc = n0 + wcol + j * 16 + m16;
#pragma unroll
      for (int r = 0; r < 4; ++r) {
        const size_t rr = m0 + wrow + i * 16 + q * 4 + r;
        out[rr * D_DIM + cc] = acc[i][j][r];
      }
    }
}

// ---------------------------------------------------------------------------
// Workspace (SZ = B*T*D = 8,388,608), total ~156 MiB (proven):
//   R0: 2*SZ fp32 (64 MiB) = scores; hosts xbf (bf16 x) early (dead by then)
//   uqb, vbf, vT, bq1(aq), bkf(ak): 5 x SZ u16 (80 MiB)
//   wqkvb 3M, woutb 1M, gqsw 1M, gksw 1M u16 (12 MiB)
// ukb (bf16 u_k) lives in d_out, fully overwritten by the final GEMM.
// attn (2*SZ u16) over [bq1|bkf] (dead after scores); o1 over uqb (dead).
// ---------------------------------------------------------------------------
extern "C" void kernel_launch(void* const* d_in, const int* in_sizes, int n_in,
                              void* d_out, int out_size, void* d_ws,
                              size_t ws_size, hipStream_t stream) {
  (void)in_sizes; (void)n_in; (void)out_size; (void)ws_size;
  const float* x = (const float*)d_in[0];
  const float* Wqkv = (const float*)d_in[1];
  const float* Wout = (const float*)d_in[2];
  const float* Gq_raw = (const float*)d_in[3];
  const float* llq = (const float*)d_in[4];
  const float* Gk_raw = (const float*)d_in[5];
  const float* llk = (const float*)d_in[6];
  float* out = (float*)d_out;

  const size_t SZ = (size_t)B_DIM * T_DIM * D_DIM;  // 8,388,608
  u16* base = (u16*)d_ws;
  float* sc = (float*)base;          // 2*SZ fp32 (= 4*SZ u16)
  u16* xbf = base;                   // bf16 x over R0 start (dead before sc)
  u16* uqb = base + 4 * SZ;
  u16* vbf = base + 5 * SZ;
  u16* vT  = base + 6 * SZ;
  u16* bq1 = base + 7 * SZ;          // final aq
  u16* bkf = base + 8 * SZ;          // final ak
  u16* wqkvb = base + 9 * SZ;                    // 3M
  u16* woutb = wqkvb + 3 * 1024 * 1024;          // 1M
  u16* gqsw = woutb + 1024 * 1024;               // 1M
  u16* gksw = gqsw + 1024 * 1024;                // 1M
  u16* ukb = (u16*)d_out;            // bf16 u_k in d_out until final GEMM
  u16* attn = bq1;                   // 2*SZ over bq1+bkf (dead after scores)
  u16* o1 = uqb;                     // dead after LCA

  const dim3 blk(256);

  // merged fp32->bf16 conversions
  cvt_all_kernel<<<dim3(12288), blk, 0, stream>>>(
      x, xbf, (int)(SZ / 4), Wqkv, wqkvb, 3 * 1024 * 1024 / 4, Wout, woutb,
      1024 * 1024 / 4);
  prep_Gsw_kernel<<<dim3(256), blk, 0, stream>>>(Gq_raw, gqsw);
  prep_Gsw_kernel<<<dim3(256), blk, 0, stream>>>(Gk_raw, gksw);

  // qkv: 1536 blocks, supertile-swizzled; bf16 outputs
  qkv_mfma_kernel<<<dim3(1536), blk, 0, stream>>>(xbf, wqkvb, uqb, ukb, vbf);
  transpose_bf16_kernel<<<dim3(16, 32, 4), blk, 0, stream>>>(vbf, vT);

  // fused LCA v15 (= v6 + per-block k-phase stagger): one dispatch
  lca_fused_kernel<<<dim3(512), dim3(512), 0, stream>>>(uqb, ukb, gqsw, gksw,
                                                        llq, llk, bq1, bkf);

  scores_mfma_kernel<<<dim3(16, 16, 4), blk, 0, stream>>>(bq1, bkf, sc);
  softmax_attn_kernel<<<dim3(B_DIM * T_DIM / 4), blk, 0, stream>>>(sc, attn);
  attnv_mfma_kernel<<<dim3(8, 16, 4), blk, 0, stream>>>(attn, vT, o1);
  out_mfma_kernel<<<dim3(8, 64), blk, 0, stream>>>(o1, woutb, out);
}

// Round 11
// 688.807 us; speedup vs baseline: 1.3857x; 1.1326x over previous
//
#include <hip/hip_runtime.h>
#include <math.h>

#define B_DIM 4
#define T_DIM 2048
#define D_DIM 1024
#define ETA 0.1f
#define N_ITERS 10

typedef unsigned short u16;
typedef unsigned char u8;
typedef long long i64;
typedef __attribute__((ext_vector_type(2))) long long i64x2; // paired fp8 frags
typedef __attribute__((ext_vector_type(8))) short bf8_t;   // 8 bf16 (4 VGPRs)
typedef __attribute__((ext_vector_type(4))) float f4_t;    // 4 fp32 acc
typedef __attribute__((ext_vector_type(16))) float f16v;   // 16 fp32 acc (32x32)

__device__ __forceinline__ u16 f2bf(float f) {
  union { float f; unsigned u; } x;
  x.f = f;
  unsigned r = x.u + 0x7FFFu + ((x.u >> 16) & 1u);  // RNE
  return (u16)(r >> 16);
}
__device__ __forceinline__ float bf2f(u16 h) {
  union { unsigned u; float f; } x;
  x.u = ((unsigned)h) << 16;
  return x.f;
}

// HW fp8 converters (gfx950 = OCP e4m3fn / e5m2; RNE, saturating).
__device__ __forceinline__ u8 f2e4m3(float f) {
  return (u8)(__builtin_amdgcn_cvt_pk_fp8_f32(f, f, 0, false) & 0xFF);
}
__device__ __forceinline__ u8 f2e5m2(float f) {
  return (u8)(__builtin_amdgcn_cvt_pk_bf8_f32(f, f, 0, false) & 0xFF);
}

__device__ __forceinline__ float soft_thresh(float v, float lam) {
  return copysignf(fmaxf(fabsf(v) - lam, 0.0f), v);
}

// ---------------------------------------------------------------------------
// Async global -> LDS staging, 16B per lane (ladder step-3, m97 pattern).
// ---------------------------------------------------------------------------
__device__ __forceinline__ void gload16(const u16* g, u16* l) {
  __builtin_amdgcn_global_load_lds(
      (const __attribute__((address_space(1))) unsigned int*)g,
      (__attribute__((address_space(3))) unsigned int*)l, 16, 0, 0);
}

// ---------------------------------------------------------------------------
// bf16 MFMA NT GEMM core v2 (R7-proven: non-LCA half 670 -> 266us). Do not
// modify.
// ---------------------------------------------------------------------------
__device__ __forceinline__ void mfma_gemm_nt(const u16* __restrict__ A,
                                             const u16* __restrict__ Bm,
                                             int lda, int ldb,
                                             int m0, int n0, int kEnd,
                                             f4_t acc[4][4]) {
  __shared__ u16 As[128][64];
  __shared__ u16 Bs[128][64];
  const int tid = threadIdx.x;
  const int lane = tid & 63;
  const int wave = tid >> 6;
  const int m16 = lane & 15;
  const int q = lane >> 4;
  const int wrow = (wave >> 1) * 64;
  const int wcol = (wave & 1) * 64;
  const int sr = tid >> 3;   // staging row base (0..31)
  const int sc8 = tid & 7;   // k-octet (8 bf16 = 16B)

  u16* aB = &As[0][0] + wave * 512;   // wave-uniform LDS dest (1 KiB / wave)
  u16* bB = &Bs[0][0] + wave * 512;

  for (int k0 = 0; k0 < kEnd; k0 += 64) {
    __syncthreads();   // previous tile fully consumed; safe to overwrite
#pragma unroll
    for (int p = 0; p < 4; ++p) {
      gload16(A + (size_t)(m0 + sr + p * 32) * lda + k0 + sc8 * 8,
              aB + p * 2048);
      gload16(Bm + (size_t)(n0 + sr + p * 32) * ldb + k0 + sc8 * 8,
              bB + p * 2048);
    }
    __syncthreads();   // compiler drains vmcnt(0) before barrier -> data ready
#pragma unroll
    for (int s = 0; s < 2; ++s) {
      bf8_t af[4], bb[4];
#pragma unroll
      for (int i = 0; i < 4; ++i)
        af[i] = *(const bf8_t*)&As[wrow + i * 16 + m16][s * 32 + q * 8];
#pragma unroll
      for (int j = 0; j < 4; ++j)
        bb[j] = *(const bf8_t*)&Bs[wcol + j * 16 + m16][s * 32 + q * 8];
#pragma unroll
      for (int i = 0; i < 4; ++i)
#pragma unroll
        for (int j = 0; j < 4; ++j)
          acc[i][j] = __builtin_amdgcn_mfma_f32_16x16x32_bf16(
              af[i], bb[j], acc[i][j], 0, 0, 0);
    }
  }
}

// C/D layout 16x16 (verified m89): col = lane&15, row = (lane>>4)*4 + reg.
#define EPI_PREAMBLE                                   \
  const int tid = threadIdx.x;                         \
  const int lane = tid & 63;                           \
  const int wave = tid >> 6;                           \
  const int m16 = lane & 15;                           \
  const int q = lane >> 4;                             \
  const int wrow = (wave >> 1) * 64;                   \
  const int wcol = (wave & 1) * 64;

// ---------------------------------------------------------------------------
// Merged fp32 -> bf16 conversion for x, Wqkv, Wout in one dispatch.
// ---------------------------------------------------------------------------
__global__ __launch_bounds__(256) void cvt_all_kernel(
    const float* __restrict__ x, u16* __restrict__ xb, int nx4,
    const float* __restrict__ w1, u16* __restrict__ w1b, int nw14,
    const float* __restrict__ w2, u16* __restrict__ w2b, int nw24) {
  int i = blockIdx.x * 256 + threadIdx.x;
  const float* src;
  u16* dst;
  if (i < nx4) {
    src = x; dst = xb;
  } else if (i < nx4 + nw14) {
    i -= nx4; src = w1; dst = w1b;
  } else {
    i -= nx4 + nw14;
    if (i >= nw24) return;
    src = w2; dst = w2b;
  }
  const float4 v = ((const float4*)src)[i];
  ushort4 o;
  o.x = f2bf(v.x); o.y = f2bf(v.y); o.z = f2bf(v.z); o.w = f2bf(v.w);
  ((ushort4*)dst)[i] = o;
}

// ---------------------------------------------------------------------------
// G -> fragment-sequential fp8 (e5m2) layout, PRE-SCALED by -ETA, with
// PAIRED k-fragments: byte = ((t*32 + cc)*64 + lane)*16 + (c&1)*8 + j holds
// G[n][k] in e5m2, n = t*32 + (lane&31), k = c*16 + (lane>>5)*8 + j, cc=c>>1.
// One 16B lane-load in the LCA c-loop delivers TWO k-slices -> bytes,
// requests, and cache lines all halve vs bf16.
// ---------------------------------------------------------------------------
__global__ __launch_bounds__(256) void prep_Gsw_kernel(
    const float* __restrict__ Graw, u8* __restrict__ Gsw8) {
  __shared__ float At[64][65];   // Graw[N0+i][K0+j]
  __shared__ float Bt[64][65];   // Graw[K0+i][N0+j]
  const int K0 = (blockIdx.x & 15) * 64;
  const int N0 = (blockIdx.x >> 4) * 64;
  const int tid = threadIdx.x;
  const int row = tid >> 2;          // 0..63
  const int c4b = tid & 3;           // float4 column group base
#pragma unroll
  for (int rep = 0; rep < 4; ++rep) {
    const int c4 = c4b + rep * 4;    // 0..15
    *(float4*)&At[row][c4 * 4] =
        *(const float4*)(Graw + (size_t)(N0 + row) * D_DIM + K0 + c4 * 4);
    *(float4*)&Bt[row][c4 * 4] =
        *(const float4*)(Graw + (size_t)(K0 + row) * D_DIM + N0 + c4 * 4);
  }
  __syncthreads();
  const float s = -ETA * 0.5f;
#pragma unroll
  for (int rep = 0; rep < 2; ++rep) {
    const int task = tid + rep * 256;   // 0..511
    const int tc = task >> 6;           // 0..7
    const int w = task & 63;
    const int t_l = tc >> 2;            // 0..1
    const int c_l = tc & 3;             // 0..3
    const int i = t_l * 32 + (w & 31);          // n-local
    const int kb = c_l * 16 + (w >> 5) * 8;     // k-local base
    union { u8 b[8]; unsigned long long v; } o;
#pragma unroll
    for (int j = 0; j < 8; ++j) {
      const int kl = kb + j;
      const float g = (N0 + i == K0 + kl)
          ? 0.0f
          : s * (At[i][kl] + Bt[kl][i]);
      o.b[j] = f2e5m2(g);
    }
    const size_t t = (size_t)(N0 >> 5) + t_l;
    const int cg = (K0 >> 4) + c_l;     // global k-slice 0..63
    const size_t cc = (size_t)(cg >> 1);
    const int half = cg & 1;
    *(unsigned long long*)(Gsw8 + ((t * 32 + cc) * 64 + w) * 16 + half * 8) =
        o.v;
  }
}

// ---------------------------------------------------------------------------
// qkv = x @ Wqkv^T -> all outputs bf16: uqb / ukb (in d_out) / vbf.
// ---------------------------------------------------------------------------
__global__ __launch_bounds__(256) void qkv_mfma_kernel(
    const u16* __restrict__ xbf, const u16* __restrict__ Wbf,
    u16* __restrict__ uqb, u16* __restrict__ ukb, u16* __restrict__ vbf) {
  const int bid = blockIdx.x;
  const int g = bid / 192;
  const int r = bid % 192;
  const int m0 = (g * 8 + (r & 7)) * 128;
  const int n0 = (r >> 3) * 128;
  f4_t acc[4][4];
#pragma unroll
  for (int i = 0; i < 4; ++i)
#pragma unroll
    for (int j = 0; j < 4; ++j) acc[i][j] = (f4_t){0.f, 0.f, 0.f, 0.f};
  mfma_gemm_nt(xbf, Wbf, D_DIM, D_DIM, m0, n0, D_DIM, acc);
  EPI_PREAMBLE
  const int which = n0 >> 10;
  u16* dst = (which == 0) ? uqb : ((which == 1) ? ukb : vbf);
  const int nloc0 = n0 & 1023;
#pragma unroll
  for (int i = 0; i < 4; ++i)
#pragma unroll
    for (int j = 0; j < 4; ++j) {
      const int cc = nloc0 + wcol + j * 16 + m16;
#pragma unroll
      for (int r2 = 0; r2 < 4; ++r2) {
        const size_t rr = m0 + wrow + i * 16 + q * 4 + r2;
        dst[rr * D_DIM + cc] = f2bf(acc[i][j][r2]);
      }
    }
}

// ---------------------------------------------------------------------------
__global__ __launch_bounds__(256) void transpose_bf16_kernel(
    const u16* __restrict__ src, u16* __restrict__ dst) {
  __shared__ short Ls[64][72];
  const int b = blockIdx.z;
  const int d0 = blockIdx.x * 64;
  const int t0 = blockIdx.y * 64;
  const int tid = threadIdx.x;
#pragma unroll
  for (int rep = 0; rep < 2; ++rep) {
    const int u = rep * 256 + tid;
    const int r = u >> 3;
    const int c8 = u & 7;
    const float4 v = *(const float4*)(src + (size_t)b * T_DIM * D_DIM +
                                      (size_t)(t0 + r) * D_DIM + d0 + c8 * 8);
    *(float4*)&Ls[r][c8 * 8] = v;
  }
  __syncthreads();
#pragma unroll
  for (int rep = 0; rep < 2; ++rep) {
    const int u = rep * 256 + tid;
    const int d = u >> 3;
    const int t8 = u & 7;
    union { u16 s[8]; float4 v; } tmp;
#pragma unroll
    for (int l = 0; l < 8; ++l) tmp.s[l] = (u16)Ls[t8 * 8 + l][d];
    *(float4*)(dst + (size_t)b * D_DIM * T_DIM + (size_t)(d0 + d) * T_DIM +
               t0 + t8 * 8) = tmp.v;
  }
}

// ---------------------------------------------------------------------------
// Fused LCA chain v16 = v6 loop SHAPE, fp8 operands (a=e4m3, G=e5m2).
// R8/R9/R10 post-mortem: prefetch depth, block alignment, and k-phase
// stagger were all null/negative -> ~30 B/cyc/CU is the sustained per-CU
// L2-return ceiling for this stream; only BYTE REDUCTION helps. fp8 halves
// G bytes AND (via paired 16B fragment loads) halves requests/lines too.
// mfma_f32_32x32x16_fp8_bf8 has the same shape/fragment mapping as the
// bf16 32x32x16 (8 elems/lane, row=lane&31, k=(lane>>5)*8+j) -> 1:1 port.
// v stays fp32 in acc all iterations; final a written to global stays bf16
// (only the iterative path carries fp8 noise; est. absmax ~0.02-0.04).
// a_lds padded to the SAME 66048-B footprint as v6 so the occupancy
// environment (and the allocator's proven 96-VGPR behavior) is unchanged.
// Init/epilogue/barriers structurally identical to v6.
// ---------------------------------------------------------------------------
__global__ __launch_bounds__(512) void lca_fused_kernel(
    const u16* __restrict__ uqb, const u16* __restrict__ ukb,
    const u8* __restrict__ Gqsw, const u8* __restrict__ Gksw,
    const float* __restrict__ llq, const float* __restrict__ llk,
    u16* __restrict__ aq_out, u16* __restrict__ ak_out) {
  __shared__ u8 a_lds8[64][1032];   // rows 0..31 used; 66048 B like v6
  const int b = blockIdx.x;
  const int chain = (b >> 2) & 1;                 // b%8: 0-3 q, 4-7 k (XCD map)
  const int mb = ((b >> 3) << 2) | (b & 3);       // 0..255
  const int m0 = mb * 32;
  const u16* __restrict__ ub = chain ? ukb : uqb;
  const u8* __restrict__ Gsw8 = chain ? Gksw : Gqsw;
  u16* __restrict__ aout = chain ? ak_out : aq_out;
  const float lam = expf(chain ? llk[0] : llq[0]);

  const int tid = threadIdx.x;
  const int lane = tid & 63;
  const int wave = tid >> 6;      // 0..7
  const int n32 = lane & 31;
  const int l5 = lane >> 5;       // 0/1
  const int col0 = wave * 128;

  f16v acc[4];                    // acc[nt] = v for this wave's 4 n-tiles

  // ---- init (iter 0): v1 = ETA*u ; a1 = soft(v1) -> LDS (e4m3) ;
  //      then pre-scale for iter 1: acc = (1-ETA)*v1 + ETA*u  (reuse uu)
#pragma unroll
  for (int nt = 0; nt < 4; ++nt) {
    const int col_g = col0 + nt * 32 + n32;
#pragma unroll
    for (int reg = 0; reg < 16; ++reg) {
      const int row = (reg & 3) + 8 * (reg >> 2) + 4 * l5;
      const float uu = bf2f(ub[(size_t)(m0 + row) * D_DIM + col_g]);
      const float v1 = ETA * uu;
      a_lds8[row][col_g] = f2e4m3(soft_thresh(v1, lam));
      acc[nt][reg] = (1.0f - ETA) * v1 + ETA * uu;
    }
  }

  // per-tile fragment base: Gsw8 + t*32KB + lane*16; step cc = +1024 B
  const u8* gb8[4];
#pragma unroll
  for (int nt = 0; nt < 4; ++nt)
    gb8[nt] = Gsw8 + ((size_t)(wave * 4 + nt) * 32) * 1024 + lane * 16;

  for (int it = 1; it < N_ITERS; ++it) {
    __syncthreads();  // a_lds complete (init or previous epilogue)

    i64x2 bb0[4], bb1[4];
#pragma unroll
    for (int nt = 0; nt < 4; ++nt) bb0[nt] = *(const i64x2*)(gb8[nt]);

#pragma unroll 1
    for (int cc = 0; cc < 32; cc += 2) {
#pragma unroll
      for (int nt = 0; nt < 4; ++nt)
        bb1[nt] = *(const i64x2*)(gb8[nt] + (size_t)(cc + 1) * 1024);
      {
        const i64 afx = *(const i64*)&a_lds8[n32][(2 * cc) * 16 + l5 * 8];
#pragma unroll
        for (int nt = 0; nt < 4; ++nt)
          acc[nt] = __builtin_amdgcn_mfma_f32_32x32x16_fp8_bf8(
              afx, bb0[nt].x, acc[nt], 0, 0, 0);
        const i64 afy = *(const i64*)&a_lds8[n32][(2 * cc + 1) * 16 + l5 * 8];
#pragma unroll
        for (int nt = 0; nt < 4; ++nt)
          acc[nt] = __builtin_amdgcn_mfma_f32_32x32x16_fp8_bf8(
              afy, bb0[nt].y, acc[nt], 0, 0, 0);
      }
      if (cc + 2 < 32) {
#pragma unroll
        for (int nt = 0; nt < 4; ++nt)
          bb0[nt] = *(const i64x2*)(gb8[nt] + (size_t)(cc + 2) * 1024);
      }
      {
        const i64 afx = *(const i64*)&a_lds8[n32][(2 * cc + 2) * 16 + l5 * 8];
#pragma unroll
        for (int nt = 0; nt < 4; ++nt)
          acc[nt] = __builtin_amdgcn_mfma_f32_32x32x16_fp8_bf8(
              afx, bb1[nt].x, acc[nt], 0, 0, 0);
        const i64 afy = *(const i64*)&a_lds8[n32][(2 * cc + 3) * 16 + l5 * 8];
#pragma unroll
        for (int nt = 0; nt < 4; ++nt)
          acc[nt] = __builtin_amdgcn_mfma_f32_32x32x16_fp8_bf8(
              afy, bb1[nt].y, acc[nt], 0, 0, 0);
      }
    }
    __syncthreads();  // all waves done READING a_lds; safe to overwrite

    // acc now holds v_{t+1}. Epilogue: a -> LDS e4m3 (bf16 global on last);
    // then pre-scale acc for the next iteration.
    const bool last = (it == N_ITERS - 1);
#pragma unroll
    for (int nt = 0; nt < 4; ++nt) {
      const int col_g = col0 + nt * 32 + n32;
#pragma unroll
      for (int reg = 0; reg < 16; ++reg) {
        const int row = (reg & 3) + 8 * (reg >> 2) + 4 * l5;
        const float av = soft_thresh(acc[nt][reg], lam);
        if (last) {
          aout[(size_t)(m0 + row) * D_DIM + col_g] = f2bf(av);
        } else {
          a_lds8[row][col_g] = f2e4m3(av);
          const float uu = bf2f(ub[(size_t)(m0 + row) * D_DIM + col_g]);
          acc[nt][reg] = (1.0f - ETA) * acc[nt][reg] + ETA * uu;
        }
      }
    }
  }
}

// ---------------------------------------------------------------------------
__global__ __launch_bounds__(256) void scores_mfma_kernel(
    const u16* __restrict__ aq, const u16* __restrict__ ak,
    float* __restrict__ sc) {
  const int b = blockIdx.z;
  const int m0 = blockIdx.y * 128;
  const int n0 = blockIdx.x * 128;
  if (n0 > m0 + 127) return;  // uniform early exit, before any barrier
  f4_t acc[4][4];
#pragma unroll
  for (int i = 0; i < 4; ++i)
#pragma unroll
    for (int j = 0; j < 4; ++j) acc[i][j] = (f4_t){0.f, 0.f, 0.f, 0.f};
  mfma_gemm_nt(aq + (size_t)b * T_DIM * D_DIM,
               ak + (size_t)b * T_DIM * D_DIM, D_DIM, D_DIM, m0, n0, D_DIM,
               acc);
  EPI_PREAMBLE
  float* out = sc + (size_t)b * T_DIM * T_DIM;
  const float scale = 0.03125f;  // 1/sqrt(1024)
#pragma unroll
  for (int i = 0; i < 4; ++i)
#pragma unroll
    for (int j = 0; j < 4; ++j) {
      const int cc = n0 + wcol + j * 16 + m16;
#pragma unroll
      for (int r = 0; r < 4; ++r) {
        const size_t rr = m0 + wrow + i * 16 + q * 4 + r;
        out[rr * T_DIM + cc] = acc[i][j][r] * scale;
      }
    }
}

// ---------------------------------------------------------------------------
// Causal softmax, one WAVE per row: row cached in 32 statically-indexed
// registers -> sc read ONCE.
// ---------------------------------------------------------------------------
__global__ __launch_bounds__(256) void softmax_attn_kernel(
    const float* __restrict__ sc, u16* __restrict__ attn) {
  const int r = blockIdx.x * 4 + (threadIdx.x >> 6);  // global row 0..8191
  const int lane = threadIdx.x & 63;
  const int b = r >> 11;
  const int i = r & (T_DIM - 1);
  const float* row = sc + ((size_t)b * T_DIM + i) * T_DIM;
  u16* arow = attn + ((size_t)b * T_DIM + i) * T_DIM;
  const int len = i + 1;

  float v[32];
  float mx = -INFINITY;
#pragma unroll
  for (int jj = 0; jj < 32; ++jj) {
    const int j = lane + jj * 64;
    v[jj] = (j < len) ? row[j] : -INFINITY;
    mx = fmaxf(mx, v[jj]);
  }
#pragma unroll
  for (int off = 32; off > 0; off >>= 1)
    mx = fmaxf(mx, __shfl_xor(mx, off));

  float sum = 0.0f;
#pragma unroll
  for (int jj = 0; jj < 32; ++jj) {
    const float e = __expf(v[jj] - mx);  // -inf -> 0
    v[jj] = e;
    sum += e;
  }
#pragma unroll
  for (int off = 32; off > 0; off >>= 1) sum += __shfl_xor(sum, off);
  const float inv = 1.0f / sum;

#pragma unroll
  for (int jj = 0; jj < 32; ++jj) {
    const int j = lane + jj * 64;
    arow[j] = (j < len) ? f2bf(v[jj] * inv) : (u16)0;
  }
}

// ---------------------------------------------------------------------------
__global__ __launch_bounds__(256) void attnv_mfma_kernel(
    const u16* __restrict__ attn, const u16* __restrict__ vT,
    u16* __restrict__ o1) {
  const int b = blockIdx.z;
  const int m0 = blockIdx.y * 128;
  const int n0 = blockIdx.x * 128;
  f4_t acc[4][4];
#pragma unroll
  for (int i = 0; i < 4; ++i)
#pragma unroll
    for (int j = 0; j < 4; ++j) acc[i][j] = (f4_t){0.f, 0.f, 0.f, 0.f};
  mfma_gemm_nt(attn + (size_t)b * T_DIM * T_DIM,
               vT + (size_t)b * D_DIM * T_DIM, T_DIM, T_DIM, m0, n0,
               m0 + 128, acc);
  EPI_PREAMBLE
  u16* out = o1 + (size_t)b * T_DIM * D_DIM;
#pragma unroll
  for (int i = 0; i < 4; ++i)
#pragma unroll
    for (int j = 0; j < 4; ++j) {
      const int cc = n0 + wcol + j * 16 + m16;
#pragma unroll
      for (int r = 0; r < 4; ++r) {
        const size_t rr = m0 + wrow + i * 16 + q * 4 + r;
        out[rr * D_DIM + cc] = f2bf(acc[i][j][r]);
      }
    }
}

// ---------------------------------------------------------------------------
__global__ __launch_bounds__(256) void out_mfma_kernel(
    const u16* __restrict__ o1, const u16* __restrict__ Wbf,
    float* __restrict__ out) {
  f4_t acc[4][4];
#pragma unroll
  for (int i = 0; i < 4; ++i)
#pragma unroll
    for (int j = 0; j < 4; ++j) acc[i][j] = (f4_t){0.f, 0.f, 0.f, 0.f};
  const int m0 = blockIdx.y * 128;
  const int n0 = blockIdx.x * 128;
  mfma_gemm_nt(o1, Wbf, D_DIM, D_DIM, m0, n0, D_DIM, acc);
  EPI_PREAMBLE
#pragma unroll
  for (int i = 0; i < 4; ++i)
#pragma unroll
    for (int j = 0; j < 4; ++j) {
      const int cc = n0 + wcol + j * 16 + m16;
#pragma unroll
      for (int r = 0; r < 4; ++r) {
        const size_t rr = m0 + wrow + i * 16 + q * 4 + r;
        out[rr * D_DIM + cc] = acc[i][j][r];
      }
    }
}

// ---------------------------------------------------------------------------
// Workspace (SZ = B*T*D = 8,388,608), total ~156 MiB (proven):
//   R0: 2*SZ fp32 (64 MiB) = scores; hosts xbf (bf16 x) early (dead by then)
//   uqb, vbf, vT, bq1(aq), bkf(ak): 5 x SZ u16 (80 MiB)
//   wqkvb 3M, woutb 1M u16; gqsw/gksw now 1 MiB fp8 each (slots unchanged)
// ukb (bf16 u_k) lives in d_out, fully overwritten by the final GEMM.
// attn (2*SZ u16) over [bq1|bkf] (dead after scores); o1 over uqb (dead).
// ---------------------------------------------------------------------------
extern "C" void kernel_launch(void* const* d_in, const int* in_sizes, int n_in,
                              void* d_out, int out_size, void* d_ws,
                              size_t ws_size, hipStream_t stream) {
  (void)in_sizes; (void)n_in; (void)out_size; (void)ws_size;
  const float* x = (const float*)d_in[0];
  const float* Wqkv = (const float*)d_in[1];
  const float* Wout = (const float*)d_in[2];
  const float* Gq_raw = (const float*)d_in[3];
  const float* llq = (const float*)d_in[4];
  const float* Gk_raw = (const float*)d_in[5];
  const float* llk = (const float*)d_in[6];
  float* out = (float*)d_out;

  const size_t SZ = (size_t)B_DIM * T_DIM * D_DIM;  // 8,388,608
  u16* base = (u16*)d_ws;
  float* sc = (float*)base;          // 2*SZ fp32 (= 4*SZ u16)
  u16* xbf = base;                   // bf16 x over R0 start (dead before sc)
  u16* uqb = base + 4 * SZ;
  u16* vbf = base + 5 * SZ;
  u16* vT  = base + 6 * SZ;
  u16* bq1 = base + 7 * SZ;          // final aq
  u16* bkf = base + 8 * SZ;          // final ak
  u16* wqkvb = base + 9 * SZ;                    // 3M
  u16* woutb = wqkvb + 3 * 1024 * 1024;          // 1M
  u8* gqsw = (u8*)(woutb + 1024 * 1024);         // 1 MiB fp8 (2 MiB slot)
  u8* gksw = gqsw + 2 * 1024 * 1024;             // 1 MiB fp8 (2 MiB slot)
  u16* ukb = (u16*)d_out;            // bf16 u_k in d_out until final GEMM
  u16* attn = bq1;                   // 2*SZ over bq1+bkf (dead after scores)
  u16* o1 = uqb;                     // dead after LCA

  const dim3 blk(256);

  // merged fp32->bf16 conversions
  cvt_all_kernel<<<dim3(12288), blk, 0, stream>>>(
      x, xbf, (int)(SZ / 4), Wqkv, wqkvb, 3 * 1024 * 1024 / 4, Wout, woutb,
      1024 * 1024 / 4);
  prep_Gsw_kernel<<<dim3(256), blk, 0, stream>>>(Gq_raw, gqsw);
  prep_Gsw_kernel<<<dim3(256), blk, 0, stream>>>(Gk_raw, gksw);

  // qkv: 1536 blocks, supertile-swizzled; bf16 outputs
  qkv_mfma_kernel<<<dim3(1536), blk, 0, stream>>>(xbf, wqkvb, uqb, ukb, vbf);
  transpose_bf16_kernel<<<dim3(16, 32, 4), blk, 0, stream>>>(vbf, vT);

  // fused LCA v16 (v6 structure, fp8 a x bf8 G operands): one dispatch
  lca_fused_kernel<<<dim3(512), dim3(512), 0, stream>>>(uqb, ukb, gqsw, gksw,
                                                        llq, llk, bq1, bkf);

  scores_mfma_kernel<<<dim3(16, 16, 4), blk, 0, stream>>>(bq1, bkf, sc);
  softmax_attn_kernel<<<dim3(B_DIM * T_DIM / 4), blk, 0, stream>>>(sc, attn);
  attnv_mfma_kernel<<<dim3(8, 16, 4), blk, 0, stream>>>(attn, vT, o1);
  out_mfma_kernel<<<dim3(8, 64), blk, 0, stream>>>(o1, woutb, out);
}